// Round 1
// baseline (401.852 us; speedup 1.0000x reference)
//
#include <hip/hip_runtime.h>
#include <cstddef>

#define N_NODES_C 100000
#define N_EDGES_C 1600000

// Bucket partition: 63 nodes per bucket, NB buckets.
#define NPB 63
#define NB 1588              // ceil(100000/63)
#define DIV_MAGIC 68174085ULL  // ceil(2^32/63); exact for d < 2^32/59
#define BCAP 1408            // max edges/bucket (mean 1008, +12.6 sigma)
#define SENT_ROW 100000      // zeroed sentinel row in feature tables

#define CONV_BLOCKS 12500    // 3.2M float4 / 256
#define WB_BLOCKS 512        // weight transpose blocks
#define P1_BLOCKS 1563       // 400128 int4 slots / 256

typedef unsigned short u16;
typedef __attribute__((ext_vector_type(8))) short bf16x8;
typedef __attribute__((ext_vector_type(4))) float f32x4;

__device__ __forceinline__ u16 f2bf(float f) {
    unsigned u = __float_as_uint(f);
    u += 0x7fffu + ((u >> 16) & 1);  // round-to-nearest-even
    return (u16)(u >> 16);
}
__device__ __forceinline__ float lo16f(unsigned v) {
    return __uint_as_float(v << 16);
}
__device__ __forceinline__ float hi16f(unsigned v) {
    return __uint_as_float(v & 0xffff0000u);
}
__device__ __forceinline__ unsigned bucket_of(int d) {
    return (unsigned)(((unsigned long long)(unsigned)d * DIV_MAGIC) >> 32);
}

// ---------------------------------------------------------------------------
// Front fused: x fp32->bf16 convert | weight transpose+convert | P1 histogram
// | sentinel-row zeroing
// ---------------------------------------------------------------------------

__global__ __launch_bounds__(256) void front_fused(
    const float* __restrict__ x, const int* __restrict__ dst,
    const float* __restrict__ W1l, const float* __restrict__ W1r,
    const float* __restrict__ W2l, const float* __restrict__ W2r,
    u16* __restrict__ x_bf, u16* __restrict__ T1l, u16* __restrict__ T1r,
    u16* __restrict__ T2l, u16* __restrict__ T2r,
    int* __restrict__ bucket_counts, u16* __restrict__ p2z) {
    const int b = blockIdx.x;
    const int t = threadIdx.x;
    if (b < CONV_BLOCKS) {
        int i = b * 256 + t;
        if (i < 3200000) {
            float4 v = ((const float4*)x)[i];
            ushort4 o;
            o.x = f2bf(v.x); o.y = f2bf(v.y); o.z = f2bf(v.z); o.w = f2bf(v.w);
            ((ushort4*)x_bf)[i] = o;
        }
    } else if (b < CONV_BLOCKS + WB_BLOCKS) {
        int id = (b - CONV_BLOCKS) * 256 + t;  // 0..131071
        int which = id >> 15;
        int r = id & 32767;
        if (which == 0) {        // [128][256] -> [256][128]
            int n = r >> 7, k = r & 127;
            T1l[r] = f2bf(W1l[k * 256 + n]);
        } else if (which == 1) {
            int n = r >> 7, k = r & 127;
            T1r[r] = f2bf(W1r[k * 256 + n]);
        } else if (which == 2) {  // [256][128] -> [128][256]
            int n = r >> 8, k = r & 255;
            T2l[r] = f2bf(W2l[k * 128 + n]);
        } else {
            int n = r >> 8, k = r & 255;
            T2r[r] = f2bf(W2r[k * 128 + n]);
        }
    } else if (b < CONV_BLOCKS + WB_BLOCKS + P1_BLOCKS) {
        __shared__ int hist[NB];
        for (int j = t; j < NB; j += 256) hist[j] = 0;
        __syncthreads();
        int i = (b - CONV_BLOCKS - WB_BLOCKS) * 256 + t;  // int4 index
        if (i * 4 < N_EDGES_C) {
            int4 d = ((const int4*)dst)[i];
            atomicAdd(&hist[bucket_of(d.x)], 1);
            atomicAdd(&hist[bucket_of(d.y)], 1);
            atomicAdd(&hist[bucket_of(d.z)], 1);
            atomicAdd(&hist[bucket_of(d.w)], 1);
        }
        __syncthreads();
        for (int j = t; j < NB; j += 256) {
            int c = hist[j];
            if (c) atomicAdd(&bucket_counts[j], c);
        }
    } else {
        // zero the sentinel rows (row SENT_ROW of x_bf and p2)
        uint4 z; z.x = 0; z.y = 0; z.z = 0; z.w = 0;
        if (t < 16)
            ((uint4*)(x_bf + (size_t)SENT_ROW * 128))[t] = z;
        else if (t < 32)
            ((uint4*)(p2z + (size_t)SENT_ROW * 128))[t - 16] = z;
    }
}

// ---------------------------------------------------------------------------
// Scan bucket counts (2048 slots, pair-per-thread) -> bucket_base + cursor
// ---------------------------------------------------------------------------

__global__ __launch_bounds__(1024) void bucket_scan(const int* __restrict__ counts,
                                                    int* __restrict__ base,
                                                    int* __restrict__ cursor) {
    __shared__ int s[1024];
    int t = threadIdx.x;
    int c0 = counts[2 * t];
    int c1 = counts[2 * t + 1];
    int v = c0 + c1;
    s[t] = v;
    __syncthreads();
    for (int off = 1; off < 1024; off <<= 1) {
        int u = (t >= off) ? s[t - off] : 0;
        __syncthreads();
        s[t] += u;
        __syncthreads();
    }
    int excl = s[t] - v;
    base[2 * t] = excl;
    cursor[2 * t] = excl;
    base[2 * t + 1] = excl + c0;
    cursor[2 * t + 1] = excl + c0;
}

// ---------------------------------------------------------------------------
// P2: partition edges into bucket-grouped packed records.
// packed = (local_dst << 17) | src   (local_dst < 63, src < 2^17)
// ---------------------------------------------------------------------------

__global__ __launch_bounds__(1024) void p2_scatter(const int* __restrict__ src,
                                                   const int* __restrict__ dst,
                                                   int* __restrict__ cursor,
                                                   unsigned* __restrict__ edge_pkt) {
    __shared__ int hist[NB];
    __shared__ int lbase[NB];
    __shared__ int cur2[NB];
    int t = threadIdx.x;
    for (int j = t; j < NB; j += 1024) { hist[j] = 0; cur2[j] = 0; }
    __syncthreads();

    int4 dd[4];
    int idx[4];
#pragma unroll
    for (int r = 0; r < 4; ++r) {
        int i = blockIdx.x * 4096 + r * 1024 + t;  // int4 index
        idx[r] = i;
        if (i * 4 < N_EDGES_C) {
            int4 d = ((const int4*)dst)[i];
            dd[r] = d;
            atomicAdd(&hist[bucket_of(d.x)], 1);
            atomicAdd(&hist[bucket_of(d.y)], 1);
            atomicAdd(&hist[bucket_of(d.z)], 1);
            atomicAdd(&hist[bucket_of(d.w)], 1);
        }
    }
    __syncthreads();
    for (int j = t; j < NB; j += 1024) {
        int c = hist[j];
        if (c) lbase[j] = atomicAdd(&cursor[j], c);
    }
    __syncthreads();

#pragma unroll
    for (int r = 0; r < 4; ++r) {
        int i = idx[r];
        if (i * 4 < N_EDGES_C) {
            int4 s4 = ((const int4*)src)[i];
            int4 d = dd[r];
            {
                unsigned b = bucket_of(d.x);
                int local = d.x - (int)b * NPB;
                int pos = lbase[b] + atomicAdd(&cur2[b], 1);
                edge_pkt[pos] = ((unsigned)local << 17) | (unsigned)s4.x;
            }
            {
                unsigned b = bucket_of(d.y);
                int local = d.y - (int)b * NPB;
                int pos = lbase[b] + atomicAdd(&cur2[b], 1);
                edge_pkt[pos] = ((unsigned)local << 17) | (unsigned)s4.y;
            }
            {
                unsigned b = bucket_of(d.z);
                int local = d.z - (int)b * NPB;
                int pos = lbase[b] + atomicAdd(&cur2[b], 1);
                edge_pkt[pos] = ((unsigned)local << 17) | (unsigned)s4.z;
            }
            {
                unsigned b = bucket_of(d.w);
                int local = d.w - (int)b * NPB;
                int pos = lbase[b] + atomicAdd(&cur2[b], 1);
                edge_pkt[pos] = ((unsigned)local << 17) | (unsigned)s4.w;
            }
        }
    }
}

// ---------------------------------------------------------------------------
// Bucketed mean aggregation, v2:
//  - 256 threads = 4 waves; wave split into 4x16-lane groups
//  - each group owns ONE node; 16 lanes x dwordx4 = one 256B row per group,
//    so one wave-instruction gathers 4 rows (1 KB); unroll 4 -> 4 KB in flight
//  - tail/idle slots load the zeroed sentinel row (cached, no masking of data)
// FINAL=false: write bf16 mean.  FINAL=true: write fp32 out = mean + resid.
// ---------------------------------------------------------------------------

template <bool FINAL>
__global__ __launch_bounds__(256, 8) void agg_bucket(const u16* __restrict__ tbl,
                                                     const int* __restrict__ base,
                                                     const unsigned* __restrict__ edge_pkt,
                                                     const u16* __restrict__ resid,
                                                     void* __restrict__ outv) {
    __shared__ unsigned se[BCAP];
    __shared__ int lhist[64];
    __shared__ int lstart[64];
    __shared__ int lcur[64];
    __shared__ int stmp[64];

    const int t = threadIdx.x;
    const int wave = t >> 6;
    const int lane = t & 63;
    const int b = blockIdx.x;

    if (t < 64) lhist[t] = 0;
    __syncthreads();

    const int ebeg = base[b];
    int ecnt = base[b + 1] - ebeg;
    if (ecnt > BCAP) ecnt = BCAP;

    for (int i = t; i < ecnt; i += 256)
        atomicAdd(&lhist[edge_pkt[ebeg + i] >> 17], 1);
    __syncthreads();

    if (t < 64) stmp[t] = lhist[t];
    __syncthreads();
    for (int off = 1; off < 64; off <<= 1) {
        int v = 0;
        if (t < 64 && t >= off) v = stmp[t - off];
        __syncthreads();
        if (t < 64) stmp[t] += v;
        __syncthreads();
    }
    if (t < 64) {
        int excl = stmp[t] - lhist[t];
        lstart[t] = excl;
        lcur[t] = excl;
    }
    __syncthreads();

    for (int i = t; i < ecnt; i += 256) {
        unsigned p = edge_pkt[ebeg + i];
        int pos = atomicAdd(&lcur[p >> 17], 1);
        se[pos] = p & 0x1ffffu;
    }
    __syncthreads();

    const int g = lane >> 4;      // group 0..3 (node slot within wave)
    const int li8 = (lane & 15) * 8;  // u16/float offset within row

    for (int pass = 0; pass < 4; ++pass) {
        int n = pass * 16 + wave * 4 + g;  // 0..63
        int node = b * NPB + n;
        int d = 0, s0 = 0;
        bool valid = (n < NPB) && (node < N_NODES_C);
        if (valid) { d = lhist[n]; s0 = lstart[n]; }
        int dmax = max(d, __shfl_xor(d, 16, 64));
        dmax = max(dmax, __shfl_xor(dmax, 32, 64));

        float a0 = 0.f, a1 = 0.f, a2 = 0.f, a3 = 0.f;
        float a4 = 0.f, a5 = 0.f, a6 = 0.f, a7 = 0.f;

        for (int j = 0; j < dmax; j += 4) {
            unsigned ix[4];
#pragma unroll
            for (int u = 0; u < 4; ++u) {
                int jj = j + u;
                int sa = s0 + jj;
                if (sa > BCAP - 1) sa = BCAP - 1;
                unsigned sv = se[sa];
                ix[u] = (jj < d) ? sv : (unsigned)SENT_ROW;
            }
            uint4 r0 = *(const uint4*)(tbl + (size_t)ix[0] * 128 + li8);
            uint4 r1 = *(const uint4*)(tbl + (size_t)ix[1] * 128 + li8);
            uint4 r2 = *(const uint4*)(tbl + (size_t)ix[2] * 128 + li8);
            uint4 r3 = *(const uint4*)(tbl + (size_t)ix[3] * 128 + li8);

            a0 += lo16f(r0.x); a1 += hi16f(r0.x);
            a2 += lo16f(r0.y); a3 += hi16f(r0.y);
            a4 += lo16f(r0.z); a5 += hi16f(r0.z);
            a6 += lo16f(r0.w); a7 += hi16f(r0.w);
            a0 += lo16f(r1.x); a1 += hi16f(r1.x);
            a2 += lo16f(r1.y); a3 += hi16f(r1.y);
            a4 += lo16f(r1.z); a5 += hi16f(r1.z);
            a6 += lo16f(r1.w); a7 += hi16f(r1.w);
            a0 += lo16f(r2.x); a1 += hi16f(r2.x);
            a2 += lo16f(r2.y); a3 += hi16f(r2.y);
            a4 += lo16f(r2.z); a5 += hi16f(r2.z);
            a6 += lo16f(r2.w); a7 += hi16f(r2.w);
            a0 += lo16f(r3.x); a1 += hi16f(r3.x);
            a2 += lo16f(r3.y); a3 += hi16f(r3.y);
            a4 += lo16f(r3.z); a5 += hi16f(r3.z);
            a6 += lo16f(r3.w); a7 += hi16f(r3.w);
        }

        if (valid) {
            float inv = d > 0 ? 1.f / (float)d : 0.f;
            if (FINAL) {
                uint4 rp = *(const uint4*)(resid + (size_t)node * 128 + li8);
                float* op = (float*)outv + (size_t)node * 128 + li8;
                float4 o0, o1;
                o0.x = a0 * inv + lo16f(rp.x);
                o0.y = a1 * inv + hi16f(rp.x);
                o0.z = a2 * inv + lo16f(rp.y);
                o0.w = a3 * inv + hi16f(rp.y);
                o1.x = a4 * inv + lo16f(rp.z);
                o1.y = a5 * inv + hi16f(rp.z);
                o1.z = a6 * inv + lo16f(rp.w);
                o1.w = a7 * inv + hi16f(rp.w);
                *(float4*)op = o0;
                *(float4*)(op + 4) = o1;
            } else {
                uint4 o;
                o.x = (unsigned)f2bf(a0 * inv) | ((unsigned)f2bf(a1 * inv) << 16);
                o.y = (unsigned)f2bf(a2 * inv) | ((unsigned)f2bf(a3 * inv) << 16);
                o.z = (unsigned)f2bf(a4 * inv) | ((unsigned)f2bf(a5 * inv) << 16);
                o.w = (unsigned)f2bf(a6 * inv) | ((unsigned)f2bf(a7 * inv) << 16);
                *(uint4*)((u16*)outv + (size_t)node * 128 + li8) = o;
            }
        }
    }
}

// ---------------------------------------------------------------------------
// Mega-fused GEMM: per 64-row M-tile,
//   phase A: h = relu(mean1@W1l + x@W1r + b1)  [64 x 256] -> LDS (A-frag order)
//   phase B: p2 = h@W2l (bf16), outp = h@W2r + b2 (bf16)
// h never touches HBM. 256 thr = 4 waves (2x2).
// ---------------------------------------------------------------------------

__global__ __launch_bounds__(256) void fused_l1l2(
    const u16* __restrict__ A1 /*mean1*/, const u16* __restrict__ A2 /*x_bf*/,
    const u16* __restrict__ T1l, const u16* __restrict__ T1r,   // [256][128]
    const u16* __restrict__ T2l, const u16* __restrict__ T2r,   // [128][256]
    const float* __restrict__ b1, const float* __restrict__ b2,
    u16* __restrict__ p2, u16* __restrict__ outp, int M) {
    alignas(16) __shared__ u16 hfrag[64 * 256];  // 32 KB, fragment-order
    alignas(16) __shared__ u16 As[64 * 32];      // 4 KB
    alignas(16) __shared__ u16 Bs[256 * 32];     // 16 KB (A: W1 tile; B: W2l|W2r)

    const int tid = threadIdx.x;
    const int lane = tid & 63;
    const int wave = tid >> 6;
    const int qm = lane & 15;
    const int quad = lane >> 4;
    const int m0 = blockIdx.x * 64;

    // ---------------- phase A: h tile ----------------
    const int wr0 = (wave >> 1) * 32;   // rows 0/32
    const int wc0 = (wave & 1) * 128;   // cols 0/128
    f32x4 acch[2][8];
#pragma unroll
    for (int i = 0; i < 2; ++i)
#pragma unroll
        for (int j = 0; j < 8; ++j) acch[i][j] = (f32x4){0.f, 0.f, 0.f, 0.f};

#pragma unroll
    for (int mat = 0; mat < 2; ++mat) {
        const u16* __restrict__ A = mat ? A2 : A1;
        const u16* __restrict__ W = mat ? T1r : T1l;
#pragma unroll
        for (int k0 = 0; k0 < 128; k0 += 32) {
            // As: 64x32 (256 chunks, 1/thread); Bs: 256x32 (1024 chunks, 4/thread)
            {
                int c = tid;
                int row = c >> 2, kc = c & 3;
                __builtin_amdgcn_global_load_lds(
                    (const __attribute__((address_space(1))) unsigned*)(
                        A + (size_t)(m0 + row) * 128 + k0 + kc * 8),
                    (__attribute__((address_space(3))) unsigned*)(As + c * 8), 16, 0, 0);
            }
#pragma unroll
            for (int r = 0; r < 4; ++r) {
                int c = r * 256 + tid;
                int row = c >> 2, kc = c & 3;
                __builtin_amdgcn_global_load_lds(
                    (const __attribute__((address_space(1))) unsigned*)(
                        W + (size_t)row * 128 + k0 + kc * 8),
                    (__attribute__((address_space(3))) unsigned*)(Bs + c * 8), 16, 0, 0);
            }
            __syncthreads();
            bf16x8 af[2], bf[8];
#pragma unroll
            for (int i = 0; i < 2; ++i)
                af[i] = *(const bf16x8*)(As + (wr0 + i * 16 + qm) * 32 + quad * 8);
#pragma unroll
            for (int j = 0; j < 8; ++j)
                bf[j] = *(const bf16x8*)(Bs + (wc0 + j * 16 + qm) * 32 + quad * 8);
#pragma unroll
            for (int i = 0; i < 2; ++i)
#pragma unroll
                for (int j = 0; j < 8; ++j)
                    acch[i][j] = __builtin_amdgcn_mfma_f32_16x16x32_bf16(
                        af[i], bf[j], acch[i][j], 0, 0, 0);
            __syncthreads();
        }
    }

    // epilogue A: +b1, relu, write to hfrag in A-fragment order
#pragma unroll
    for (int j = 0; j < 8; ++j) {
        int n = wc0 + j * 16 + qm;
        float bb = b1[n];
        int ks = n >> 5, quadB = (n >> 3) & 3, jB = n & 7;
#pragma unroll
        for (int i = 0; i < 2; ++i) {
#pragma unroll
            for (int r = 0; r < 4; ++r) {
                int mloc = wr0 + i * 16 + quad * 4 + r;
                float v = fmaxf(acch[i][j][r] + bb, 0.f);
                hfrag[((ks * 4 + (mloc >> 4)) * 16 + (mloc & 15)) * 32 + quadB * 8 + jB] =
                    f2bf(v);
            }
        }
    }
    __syncthreads();

    // ---------------- phase B: p2 / outp ----------------
    const int wrB = (wave >> 1) * 32;   // rows 0/32
    const int wcB = (wave & 1) * 64;    // cols 0/64 (of 128)
    f32x4 accp[2][4], acco[2][4];
#pragma unroll
    for (int i = 0; i < 2; ++i)
#pragma unroll
        for (int j = 0; j < 4; ++j) {
            accp[i][j] = (f32x4){0.f, 0.f, 0.f, 0.f};
            acco[i][j] = (f32x4){0.f, 0.f, 0.f, 0.f};
        }

#pragma unroll
    for (int ks = 0; ks < 8; ++ks) {
        // stage W2l|W2r k-chunk: Bs[mat][128][32], 1024 chunks, 4/thread
#pragma unroll
        for (int r = 0; r < 4; ++r) {
            int c = r * 256 + tid;
            int matc = c >> 9;
            int row = (c >> 2) & 127;
            int kc = c & 3;
            const u16* W = matc ? T2r : T2l;
            __builtin_amdgcn_global_load_lds(
                (const __attribute__((address_space(1))) unsigned*)(
                    W + (size_t)row * 256 + ks * 32 + kc * 8),
                (__attribute__((address_space(3))) unsigned*)(Bs + c * 8), 16, 0, 0);
        }
        __syncthreads();
        bf16x8 af[2], bfl[4], bfr[4];
#pragma unroll
        for (int i = 0; i < 2; ++i)
            af[i] = *(const bf16x8*)(hfrag +
                                     ((ks * 4 + (wrB >> 4) + i) * 16 + qm) * 32 + quad * 8);
#pragma unroll
        for (int j = 0; j < 4; ++j) {
            bfl[j] = *(const bf16x8*)(Bs + (wcB + j * 16 + qm) * 32 + quad * 8);
            bfr[j] = *(const bf16x8*)(Bs + 4096 + (wcB + j * 16 + qm) * 32 + quad * 8);
        }
#pragma unroll
        for (int i = 0; i < 2; ++i)
#pragma unroll
            for (int j = 0; j < 4; ++j) {
                accp[i][j] = __builtin_amdgcn_mfma_f32_16x16x32_bf16(af[i], bfl[j],
                                                                    accp[i][j], 0, 0, 0);
                acco[i][j] = __builtin_amdgcn_mfma_f32_16x16x32_bf16(af[i], bfr[j],
                                                                    acco[i][j], 0, 0, 0);
            }
        __syncthreads();
    }

    // epilogue B
#pragma unroll
    for (int j = 0; j < 4; ++j) {
        int n = wcB + j * 16 + qm;
        float bb2 = b2[n];
#pragma unroll
        for (int i = 0; i < 2; ++i) {
#pragma unroll
            for (int r = 0; r < 4; ++r) {
                int row = m0 + wrB + i * 16 + quad * 4 + r;
                if (row < M) {
                    p2[(size_t)row * 128 + n] = f2bf(accp[i][j][r]);
                    outp[(size_t)row * 128 + n] = f2bf(acco[i][j][r] + bb2);
                }
            }
        }
    }
}

// ---------------------------------------------------------------------------
// launch
// ---------------------------------------------------------------------------

extern "C" void kernel_launch(void* const* d_in, const int* in_sizes, int n_in,
                              void* d_out, int out_size, void* d_ws, size_t ws_size,
                              hipStream_t stream) {
    const float* x = (const float*)d_in[0];
    const int* ei = (const int*)d_in[1];
    const float* W1l = (const float*)d_in[2];
    const float* b1 = (const float*)d_in[3];
    const float* W1r = (const float*)d_in[4];
    const float* W2l = (const float*)d_in[5];
    const float* b2 = (const float*)d_in[6];
    const float* W2r = (const float*)d_in[7];
    float* out = (float*)d_out;

    const int* src = ei;
    const int* dst = ei + N_EDGES_C;

    // int workspace region (first 8 MiB)
    int* iw = (int*)d_ws;
    int* bucket_counts = iw;                      // 2048
    int* bucket_base = iw + 2048;                 // 2048 (NB+1 used)
    int* cursor = iw + 4096;                      // 2048
    unsigned* edge_pkt = (unsigned*)(iw + 6144);  // 1.6M ints -> ends 1606144
    u16* T1l = (u16*)(iw + 1606144);              // 4 x 32768 u16 = 256 KB
    u16* T1r = T1l + 32768;
    u16* T2l = T1r + 32768;
    u16* T2r = T2l + 32768;                       // ends ~6.7 MB < 8 MiB
    // bf16 region at byte offset 8 MiB; stride 12.85M u16 (pad for OOB tile reads
    // and the sentinel zero row at row 100000)
    u16* ub = (u16*)((char*)d_ws + (8u << 20));
    u16* x_bf = ub;                               // [100001][128]
    u16* mean1 = ub + 12850000;                   // [100000][128]
    u16* p2 = ub + 25700000;                      // [100001][128]
    u16* outp = ub + 38550000;                    // [100000][128]

    hipMemsetAsync(bucket_counts, 0, 2048 * sizeof(int), stream);

    front_fused<<<CONV_BLOCKS + WB_BLOCKS + P1_BLOCKS + 1, 256, 0, stream>>>(
        x, dst, W1l, W1r, W2l, W2r, x_bf, T1l, T1r, T2l, T2r, bucket_counts, p2);
    bucket_scan<<<1, 1024, 0, stream>>>(bucket_counts, bucket_base, cursor);
    p2_scatter<<<(N_EDGES_C / 4 + 4095) / 4096, 1024, 0, stream>>>(src, dst, cursor,
                                                                   edge_pkt);

    // mean1 = mean_{src->node} x
    agg_bucket<false><<<NB, 256, 0, stream>>>(x_bf, bucket_base, edge_pkt, nullptr,
                                              mean1);
    // h = relu(mean1@W1l + x@W1r + b1);  p2 = h@W2l;  outp = h@W2r + b2
    fused_l1l2<<<(N_NODES_C + 63) / 64, 256, 0, stream>>>(
        mean1, x_bf, T1l, T1r, T2l, T2r, b1, b2, p2, outp, N_NODES_C);
    // out = mean_{src->node} p2 + outp   (fp32)
    agg_bucket<true><<<NB, 256, 0, stream>>>(p2, bucket_base, edge_pkt, outp, out);
}

// Round 2
// 396.917 us; speedup vs baseline: 1.0124x; 1.0124x over previous
//
#include <hip/hip_runtime.h>
#include <cstddef>

#define N_NODES_C 100000
#define N_EDGES_C 1600000

// Bucket partition: 64 nodes per bucket (= GEMM M-tile), NB buckets.
#define NPB 64
#define NB 1563              // ceil(100000/64)
#define BCAP 1408            // max edges/bucket (mean 1024, +12 sigma)
#define SENT_ROW 100000      // zeroed sentinel row in feature tables

#define CONV_BLOCKS 12500    // 3.2M float4 / 256
#define WB_BLOCKS 512        // weight transpose blocks
#define P1_BLOCKS 1563       // 400128 int4 slots / 256

typedef unsigned short u16;
typedef __attribute__((ext_vector_type(8))) short bf16x8;
typedef __attribute__((ext_vector_type(4))) float f32x4;

__device__ __forceinline__ u16 f2bf(float f) {
    unsigned u = __float_as_uint(f);
    u += 0x7fffu + ((u >> 16) & 1);  // round-to-nearest-even
    return (u16)(u >> 16);
}
__device__ __forceinline__ float lo16f(unsigned v) {
    return __uint_as_float(v << 16);
}
__device__ __forceinline__ float hi16f(unsigned v) {
    return __uint_as_float(v & 0xffff0000u);
}

// ---------------------------------------------------------------------------
// Front fused: x fp32->bf16 convert | weight transpose+convert | P1 histogram
// | sentinel-row zeroing
// ---------------------------------------------------------------------------

__global__ __launch_bounds__(256) void front_fused(
    const float* __restrict__ x, const int* __restrict__ dst,
    const float* __restrict__ W1l, const float* __restrict__ W1r,
    const float* __restrict__ W2l, const float* __restrict__ W2r,
    u16* __restrict__ x_bf, u16* __restrict__ T1l, u16* __restrict__ T1r,
    u16* __restrict__ T2l, u16* __restrict__ T2r,
    int* __restrict__ bucket_counts, u16* __restrict__ p2z) {
    const int b = blockIdx.x;
    const int t = threadIdx.x;
    if (b < CONV_BLOCKS) {
        int i = b * 256 + t;
        if (i < 3200000) {
            float4 v = ((const float4*)x)[i];
            ushort4 o;
            o.x = f2bf(v.x); o.y = f2bf(v.y); o.z = f2bf(v.z); o.w = f2bf(v.w);
            ((ushort4*)x_bf)[i] = o;
        }
    } else if (b < CONV_BLOCKS + WB_BLOCKS) {
        int id = (b - CONV_BLOCKS) * 256 + t;  // 0..131071
        int which = id >> 15;
        int r = id & 32767;
        if (which == 0) {        // [128][256] -> [256][128]
            int n = r >> 7, k = r & 127;
            T1l[r] = f2bf(W1l[k * 256 + n]);
        } else if (which == 1) {
            int n = r >> 7, k = r & 127;
            T1r[r] = f2bf(W1r[k * 256 + n]);
        } else if (which == 2) {  // [256][128] -> [128][256]
            int n = r >> 8, k = r & 255;
            T2l[r] = f2bf(W2l[k * 128 + n]);
        } else {
            int n = r >> 8, k = r & 255;
            T2r[r] = f2bf(W2r[k * 128 + n]);
        }
    } else if (b < CONV_BLOCKS + WB_BLOCKS + P1_BLOCKS) {
        __shared__ int hist[NB];
        for (int j = t; j < NB; j += 256) hist[j] = 0;
        __syncthreads();
        int i = (b - CONV_BLOCKS - WB_BLOCKS) * 256 + t;  // int4 index
        if (i * 4 < N_EDGES_C) {
            int4 d = ((const int4*)dst)[i];
            atomicAdd(&hist[d.x >> 6], 1);
            atomicAdd(&hist[d.y >> 6], 1);
            atomicAdd(&hist[d.z >> 6], 1);
            atomicAdd(&hist[d.w >> 6], 1);
        }
        __syncthreads();
        for (int j = t; j < NB; j += 256) {
            int c = hist[j];
            if (c) atomicAdd(&bucket_counts[j], c);
        }
    } else {
        // zero the sentinel rows (row SENT_ROW of x_bf and p2)
        uint4 z; z.x = 0; z.y = 0; z.z = 0; z.w = 0;
        if (t < 16)
            ((uint4*)(x_bf + (size_t)SENT_ROW * 128))[t] = z;
        else if (t < 32)
            ((uint4*)(p2z + (size_t)SENT_ROW * 128))[t - 16] = z;
    }
}

// ---------------------------------------------------------------------------
// Scan bucket counts (2048 slots, pair-per-thread) -> bucket_base + cursor
// ---------------------------------------------------------------------------

__global__ __launch_bounds__(1024) void bucket_scan(const int* __restrict__ counts,
                                                    int* __restrict__ base,
                                                    int* __restrict__ cursor) {
    __shared__ int s[1024];
    int t = threadIdx.x;
    int c0 = counts[2 * t];
    int c1 = counts[2 * t + 1];
    int v = c0 + c1;
    s[t] = v;
    __syncthreads();
    for (int off = 1; off < 1024; off <<= 1) {
        int u = (t >= off) ? s[t - off] : 0;
        __syncthreads();
        s[t] += u;
        __syncthreads();
    }
    int excl = s[t] - v;
    base[2 * t] = excl;
    cursor[2 * t] = excl;
    base[2 * t + 1] = excl + c0;
    cursor[2 * t + 1] = excl + c0;
}

// ---------------------------------------------------------------------------
// P2: partition edges into bucket-grouped packed records.
// packed = (local_dst << 17) | src   (local_dst < 64, src < 2^17)
// ---------------------------------------------------------------------------

__global__ __launch_bounds__(1024) void p2_scatter(const int* __restrict__ src,
                                                   const int* __restrict__ dst,
                                                   int* __restrict__ cursor,
                                                   unsigned* __restrict__ edge_pkt) {
    __shared__ int hist[NB];
    __shared__ int lbase[NB];
    __shared__ int cur2[NB];
    int t = threadIdx.x;
    for (int j = t; j < NB; j += 1024) { hist[j] = 0; cur2[j] = 0; }
    __syncthreads();

    int4 dd[4];
    int idx[4];
#pragma unroll
    for (int r = 0; r < 4; ++r) {
        int i = blockIdx.x * 4096 + r * 1024 + t;  // int4 index
        idx[r] = i;
        if (i * 4 < N_EDGES_C) {
            int4 d = ((const int4*)dst)[i];
            dd[r] = d;
            atomicAdd(&hist[d.x >> 6], 1);
            atomicAdd(&hist[d.y >> 6], 1);
            atomicAdd(&hist[d.z >> 6], 1);
            atomicAdd(&hist[d.w >> 6], 1);
        }
    }
    __syncthreads();
    for (int j = t; j < NB; j += 1024) {
        int c = hist[j];
        if (c) lbase[j] = atomicAdd(&cursor[j], c);
    }
    __syncthreads();

#pragma unroll
    for (int r = 0; r < 4; ++r) {
        int i = idx[r];
        if (i * 4 < N_EDGES_C) {
            int4 s4 = ((const int4*)src)[i];
            int4 d = dd[r];
            {
                int bk = d.x >> 6, local = d.x & 63;
                int pos = lbase[bk] + atomicAdd(&cur2[bk], 1);
                edge_pkt[pos] = ((unsigned)local << 17) | (unsigned)s4.x;
            }
            {
                int bk = d.y >> 6, local = d.y & 63;
                int pos = lbase[bk] + atomicAdd(&cur2[bk], 1);
                edge_pkt[pos] = ((unsigned)local << 17) | (unsigned)s4.y;
            }
            {
                int bk = d.z >> 6, local = d.z & 63;
                int pos = lbase[bk] + atomicAdd(&cur2[bk], 1);
                edge_pkt[pos] = ((unsigned)local << 17) | (unsigned)s4.z;
            }
            {
                int bk = d.w >> 6, local = d.w & 63;
                int pos = lbase[bk] + atomicAdd(&cur2[bk], 1);
                edge_pkt[pos] = ((unsigned)local << 17) | (unsigned)s4.w;
            }
        }
    }
}

// ---------------------------------------------------------------------------
// Fused per-bucket kernel: bucket b owns nodes [b*64, b*64+64).
//   sort: LDS counting-sort of the bucket's edges by local dst
//   gather: mean_{src->node} x_bf  -> meanS (LDS, chunk-swizzled)
//   xS: block's own x rows staged once (contiguous, pre-swizzled source)
//   phase A: h = relu(meanS@W1l + xS@W1r + b1) -> hfrag (aliases meanS|xS)
//   phase B: p2 = h@W2l, outp = h@W2r + b2
// Gather (fabric-bound) of one block overlaps MFMA of the co-resident block.
// ---------------------------------------------------------------------------

__global__ __launch_bounds__(256, 2) void fused_gemm_agg(
    const u16* __restrict__ x_bf,
    const int* __restrict__ base, const unsigned* __restrict__ edge_pkt,
    const u16* __restrict__ T1l, const u16* __restrict__ T1r,   // [256][128]
    const u16* __restrict__ T2l, const u16* __restrict__ T2r,   // [128][256]
    const float* __restrict__ b1, const float* __restrict__ b2,
    u16* __restrict__ p2, u16* __restrict__ outp, int M) {
    alignas(16) __shared__ u16 uni[64 * 256];  // 32KB: [meanS|xS] then hfrag
    alignas(16) __shared__ u16 Bs[8192];       // 16KB weight staging
    __shared__ unsigned se[BCAP];
    __shared__ int lhist[64];
    __shared__ int lstart[64];
    __shared__ int lcur[64];
    __shared__ int stmp[64];

    u16* const meanS = uni;           // [64][128], 16B-chunk ^ (row&7)
    u16* const xS = uni + 64 * 128;   // [64][128], same swizzle
    u16* const hfrag = uni;           // phase-B alias (32KB)

    const int tid = threadIdx.x;
    const int lane = tid & 63;
    const int wave = tid >> 6;
    const int qm = lane & 15;
    const int quad = lane >> 4;
    const int b = blockIdx.x;
    const int m0 = b * 64;

    // ---- issue xS staging early (lands during sort) ----
#pragma unroll
    for (int r = 0; r < 4; ++r) {
        int c = r * 256 + tid;          // 1024 chunks of 16B
        int row = c >> 4, q16 = c & 15;
        __builtin_amdgcn_global_load_lds(
            (const __attribute__((address_space(1))) unsigned*)(
                x_bf + (size_t)(m0 + row) * 128 + ((q16 ^ (row & 7)) * 8)),
            (__attribute__((address_space(3))) unsigned*)(xS + c * 8), 16, 0, 0);
    }

    if (tid < 64) lhist[tid] = 0;
    __syncthreads();

    const int ebeg = base[b];
    int ecnt = base[b + 1] - ebeg;
    if (ecnt > BCAP) ecnt = BCAP;

    for (int i = tid; i < ecnt; i += 256)
        atomicAdd(&lhist[edge_pkt[ebeg + i] >> 17], 1);
    __syncthreads();

    if (tid < 64) stmp[tid] = lhist[tid];
    __syncthreads();
    for (int off = 1; off < 64; off <<= 1) {
        int v = 0;
        if (tid < 64 && tid >= off) v = stmp[tid - off];
        __syncthreads();
        if (tid < 64) stmp[tid] += v;
        __syncthreads();
    }
    if (tid < 64) {
        int excl = stmp[tid] - lhist[tid];
        lstart[tid] = excl;
        lcur[tid] = excl;
    }
    __syncthreads();

    for (int i = tid; i < ecnt; i += 256) {
        unsigned p = edge_pkt[ebeg + i];
        int pos = atomicAdd(&lcur[p >> 17], 1);
        se[pos] = p & 0x1ffffu;
    }
    __syncthreads();

    // ---- gather + mean -> meanS (bf16, swizzled) ----
    const int g = quad;               // 16-lane group within wave
    const int li16 = qm;              // 16B chunk within row
    const int li8 = li16 * 8;

    for (int pass = 0; pass < 4; ++pass) {
        int n = pass * 16 + wave * 4 + g;   // 0..63
        int d = lhist[n];
        int s0 = lstart[n];
        int dmax = max(d, __shfl_xor(d, 16, 64));
        dmax = max(dmax, __shfl_xor(dmax, 32, 64));

        float a0 = 0.f, a1 = 0.f, a2 = 0.f, a3 = 0.f;
        float a4 = 0.f, a5 = 0.f, a6 = 0.f, a7 = 0.f;

        for (int j = 0; j < dmax; j += 4) {
            unsigned ix[4];
#pragma unroll
            for (int u = 0; u < 4; ++u) {
                int jj = j + u;
                int sa = s0 + jj;
                if (sa > BCAP - 1) sa = BCAP - 1;
                unsigned sv = se[sa];
                ix[u] = (jj < d) ? sv : (unsigned)SENT_ROW;
            }
            uint4 r0 = *(const uint4*)(x_bf + (size_t)ix[0] * 128 + li8);
            uint4 r1 = *(const uint4*)(x_bf + (size_t)ix[1] * 128 + li8);
            uint4 r2 = *(const uint4*)(x_bf + (size_t)ix[2] * 128 + li8);
            uint4 r3 = *(const uint4*)(x_bf + (size_t)ix[3] * 128 + li8);

            a0 += lo16f(r0.x); a1 += hi16f(r0.x);
            a2 += lo16f(r0.y); a3 += hi16f(r0.y);
            a4 += lo16f(r0.z); a5 += hi16f(r0.z);
            a6 += lo16f(r0.w); a7 += hi16f(r0.w);
            a0 += lo16f(r1.x); a1 += hi16f(r1.x);
            a2 += lo16f(r1.y); a3 += hi16f(r1.y);
            a4 += lo16f(r1.z); a5 += hi16f(r1.z);
            a6 += lo16f(r1.w); a7 += hi16f(r1.w);
            a0 += lo16f(r2.x); a1 += hi16f(r2.x);
            a2 += lo16f(r2.y); a3 += hi16f(r2.y);
            a4 += lo16f(r2.z); a5 += hi16f(r2.z);
            a6 += lo16f(r2.w); a7 += hi16f(r2.w);
            a0 += lo16f(r3.x); a1 += hi16f(r3.x);
            a2 += lo16f(r3.y); a3 += hi16f(r3.y);
            a4 += lo16f(r3.z); a5 += hi16f(r3.z);
            a6 += lo16f(r3.w); a7 += hi16f(r3.w);
        }

        float inv = d > 0 ? 1.f / (float)d : 0.f;
        uint4 o;
        o.x = (unsigned)f2bf(a0 * inv) | ((unsigned)f2bf(a1 * inv) << 16);
        o.y = (unsigned)f2bf(a2 * inv) | ((unsigned)f2bf(a3 * inv) << 16);
        o.z = (unsigned)f2bf(a4 * inv) | ((unsigned)f2bf(a5 * inv) << 16);
        o.w = (unsigned)f2bf(a6 * inv) | ((unsigned)f2bf(a7 * inv) << 16);
        *(uint4*)(meanS + n * 128 + ((li16 ^ (n & 7)) * 8)) = o;
    }
    __syncthreads();

    // ---------------- phase A: h tile ----------------
    const int wr0 = (wave >> 1) * 32;   // rows 0/32
    const int wc0 = (wave & 1) * 128;   // cols 0/128
    f32x4 acch[2][8];
#pragma unroll
    for (int i = 0; i < 2; ++i)
#pragma unroll
        for (int j = 0; j < 8; ++j) acch[i][j] = (f32x4){0.f, 0.f, 0.f, 0.f};

#pragma unroll
    for (int mat = 0; mat < 2; ++mat) {
        const u16* __restrict__ W = mat ? T1r : T1l;
        const u16* Al = mat ? xS : meanS;
#pragma unroll
        for (int k0 = 0; k0 < 128; k0 += 32) {
            // Bs: 256x32 (1024 chunks, 4/thread), source pre-swizzled (^row&3)
#pragma unroll
            for (int r = 0; r < 4; ++r) {
                int c = r * 256 + tid;
                int row = c >> 2, kc = c & 3;
                __builtin_amdgcn_global_load_lds(
                    (const __attribute__((address_space(1))) unsigned*)(
                        W + (size_t)row * 128 + k0 + ((kc ^ (row & 3)) * 8)),
                    (__attribute__((address_space(3))) unsigned*)(Bs + c * 8), 16, 0, 0);
            }
            __syncthreads();
            int ch0 = k0 >> 3;
            bf16x8 af[2], bfv[8];
#pragma unroll
            for (int i = 0; i < 2; ++i) {
                int row = wr0 + i * 16 + qm;
                af[i] = *(const bf16x8*)(Al + row * 128 +
                                         (((ch0 + quad) ^ (row & 7)) * 8));
            }
#pragma unroll
            for (int j = 0; j < 8; ++j) {
                int rB = wc0 + j * 16 + qm;
                bfv[j] = *(const bf16x8*)(Bs + rB * 32 + ((quad ^ (rB & 3)) * 8));
            }
#pragma unroll
            for (int i = 0; i < 2; ++i)
#pragma unroll
                for (int j = 0; j < 8; ++j)
                    acch[i][j] = __builtin_amdgcn_mfma_f32_16x16x32_bf16(
                        af[i], bfv[j], acch[i][j], 0, 0, 0);
            __syncthreads();
        }
    }

    // epilogue A: +b1, relu, write to hfrag (aliases meanS/xS — dead now)
#pragma unroll
    for (int j = 0; j < 8; ++j) {
        int n = wc0 + j * 16 + qm;
        float bb = b1[n];
        int ks = n >> 5, quadB = (n >> 3) & 3, jB = n & 7;
#pragma unroll
        for (int i = 0; i < 2; ++i) {
#pragma unroll
            for (int r = 0; r < 4; ++r) {
                int mloc = wr0 + i * 16 + quad * 4 + r;
                float v = fmaxf(acch[i][j][r] + bb, 0.f);
                hfrag[((ks * 4 + (mloc >> 4)) * 16 + (mloc & 15)) * 32 + quadB * 8 + jB] =
                    f2bf(v);
            }
        }
    }
    __syncthreads();

    // ---------------- phase B: p2 / outp ----------------
    const int wrB = (wave >> 1) * 32;   // rows 0/32
    const int wcB = (wave & 1) * 64;    // cols 0/64 (of 128)
    f32x4 accp[2][4], acco[2][4];
#pragma unroll
    for (int i = 0; i < 2; ++i)
#pragma unroll
        for (int j = 0; j < 4; ++j) {
            accp[i][j] = (f32x4){0.f, 0.f, 0.f, 0.f};
            acco[i][j] = (f32x4){0.f, 0.f, 0.f, 0.f};
        }

#pragma unroll
    for (int ks = 0; ks < 8; ++ks) {
        // stage W2l|W2r k-chunk: Bs[mat][128][32], 1024 chunks, 4/thread
#pragma unroll
        for (int r = 0; r < 4; ++r) {
            int c = r * 256 + tid;
            int matc = c >> 9;
            int row = (c >> 2) & 127;
            int kc = c & 3;
            const u16* W = matc ? T2r : T2l;
            __builtin_amdgcn_global_load_lds(
                (const __attribute__((address_space(1))) unsigned*)(
                    W + (size_t)row * 256 + ks * 32 + ((kc ^ (row & 3)) * 8)),
                (__attribute__((address_space(3))) unsigned*)(Bs + c * 8), 16, 0, 0);
        }
        __syncthreads();
        bf16x8 af[2], bfl[4], bfr[4];
#pragma unroll
        for (int i = 0; i < 2; ++i)
            af[i] = *(const bf16x8*)(hfrag +
                                     ((ks * 4 + (wrB >> 4) + i) * 16 + qm) * 32 + quad * 8);
#pragma unroll
        for (int j = 0; j < 4; ++j) {
            int rB = wcB + j * 16 + qm;
            bfl[j] = *(const bf16x8*)(Bs + rB * 32 + ((quad ^ (rB & 3)) * 8));
            bfr[j] = *(const bf16x8*)(Bs + 4096 + rB * 32 + ((quad ^ (rB & 3)) * 8));
        }
#pragma unroll
        for (int i = 0; i < 2; ++i)
#pragma unroll
            for (int j = 0; j < 4; ++j) {
                accp[i][j] = __builtin_amdgcn_mfma_f32_16x16x32_bf16(af[i], bfl[j],
                                                                    accp[i][j], 0, 0, 0);
                acco[i][j] = __builtin_amdgcn_mfma_f32_16x16x32_bf16(af[i], bfr[j],
                                                                    acco[i][j], 0, 0, 0);
            }
        __syncthreads();
    }

    // epilogue B
#pragma unroll
    for (int j = 0; j < 4; ++j) {
        int n = wcB + j * 16 + qm;
        float bb2 = b2[n];
#pragma unroll
        for (int i = 0; i < 2; ++i) {
#pragma unroll
            for (int r = 0; r < 4; ++r) {
                int row = m0 + wrB + i * 16 + quad * 4 + r;
                if (row < M) {
                    p2[(size_t)row * 128 + n] = f2bf(accp[i][j][r]);
                    outp[(size_t)row * 128 + n] = f2bf(acco[i][j][r] + bb2);
                }
            }
        }
    }
}

// ---------------------------------------------------------------------------
// Final aggregation: out = mean_{src->node} p2 + outp   (fp32)
// ---------------------------------------------------------------------------

__global__ __launch_bounds__(256, 8) void agg_final(const u16* __restrict__ tbl,
                                                    const int* __restrict__ base,
                                                    const unsigned* __restrict__ edge_pkt,
                                                    const u16* __restrict__ resid,
                                                    float* __restrict__ outv) {
    __shared__ unsigned se[BCAP];
    __shared__ int lhist[64];
    __shared__ int lstart[64];
    __shared__ int lcur[64];
    __shared__ int stmp[64];

    const int t = threadIdx.x;
    const int wave = t >> 6;
    const int lane = t & 63;
    const int b = blockIdx.x;

    if (t < 64) lhist[t] = 0;
    __syncthreads();

    const int ebeg = base[b];
    int ecnt = base[b + 1] - ebeg;
    if (ecnt > BCAP) ecnt = BCAP;

    for (int i = t; i < ecnt; i += 256)
        atomicAdd(&lhist[edge_pkt[ebeg + i] >> 17], 1);
    __syncthreads();

    if (t < 64) stmp[t] = lhist[t];
    __syncthreads();
    for (int off = 1; off < 64; off <<= 1) {
        int v = 0;
        if (t < 64 && t >= off) v = stmp[t - off];
        __syncthreads();
        if (t < 64) stmp[t] += v;
        __syncthreads();
    }
    if (t < 64) {
        int excl = stmp[t] - lhist[t];
        lstart[t] = excl;
        lcur[t] = excl;
    }
    __syncthreads();

    for (int i = t; i < ecnt; i += 256) {
        unsigned p = edge_pkt[ebeg + i];
        int pos = atomicAdd(&lcur[p >> 17], 1);
        se[pos] = p & 0x1ffffu;
    }
    __syncthreads();

    const int g = lane >> 4;
    const int li8 = (lane & 15) * 8;

    for (int pass = 0; pass < 4; ++pass) {
        int n = pass * 16 + wave * 4 + g;   // 0..63
        int node = b * NPB + n;
        bool valid = node < N_NODES_C;
        int d = 0, s0 = 0;
        if (valid) { d = lhist[n]; s0 = lstart[n]; }
        int dmax = max(d, __shfl_xor(d, 16, 64));
        dmax = max(dmax, __shfl_xor(dmax, 32, 64));

        float a0 = 0.f, a1 = 0.f, a2 = 0.f, a3 = 0.f;
        float a4 = 0.f, a5 = 0.f, a6 = 0.f, a7 = 0.f;

        for (int j = 0; j < dmax; j += 4) {
            unsigned ix[4];
#pragma unroll
            for (int u = 0; u < 4; ++u) {
                int jj = j + u;
                int sa = s0 + jj;
                if (sa > BCAP - 1) sa = BCAP - 1;
                unsigned sv = se[sa];
                ix[u] = (jj < d) ? sv : (unsigned)SENT_ROW;
            }
            uint4 r0 = *(const uint4*)(tbl + (size_t)ix[0] * 128 + li8);
            uint4 r1 = *(const uint4*)(tbl + (size_t)ix[1] * 128 + li8);
            uint4 r2 = *(const uint4*)(tbl + (size_t)ix[2] * 128 + li8);
            uint4 r3 = *(const uint4*)(tbl + (size_t)ix[3] * 128 + li8);

            a0 += lo16f(r0.x); a1 += hi16f(r0.x);
            a2 += lo16f(r0.y); a3 += hi16f(r0.y);
            a4 += lo16f(r0.z); a5 += hi16f(r0.z);
            a6 += lo16f(r0.w); a7 += hi16f(r0.w);
            a0 += lo16f(r1.x); a1 += hi16f(r1.x);
            a2 += lo16f(r1.y); a3 += hi16f(r1.y);
            a4 += lo16f(r1.z); a5 += hi16f(r1.z);
            a6 += lo16f(r1.w); a7 += hi16f(r1.w);
            a0 += lo16f(r2.x); a1 += hi16f(r2.x);
            a2 += lo16f(r2.y); a3 += hi16f(r2.y);
            a4 += lo16f(r2.z); a5 += hi16f(r2.z);
            a6 += lo16f(r2.w); a7 += hi16f(r2.w);
            a0 += lo16f(r3.x); a1 += hi16f(r3.x);
            a2 += lo16f(r3.y); a3 += hi16f(r3.y);
            a4 += lo16f(r3.z); a5 += hi16f(r3.z);
            a6 += lo16f(r3.w); a7 += hi16f(r3.w);
        }

        if (valid) {
            float inv = d > 0 ? 1.f / (float)d : 0.f;
            uint4 rp = *(const uint4*)(resid + (size_t)node * 128 + li8);
            float* op = outv + (size_t)node * 128 + li8;
            float4 o0, o1;
            o0.x = a0 * inv + lo16f(rp.x);
            o0.y = a1 * inv + hi16f(rp.x);
            o0.z = a2 * inv + lo16f(rp.y);
            o0.w = a3 * inv + hi16f(rp.y);
            o1.x = a4 * inv + lo16f(rp.z);
            o1.y = a5 * inv + hi16f(rp.z);
            o1.z = a6 * inv + lo16f(rp.w);
            o1.w = a7 * inv + hi16f(rp.w);
            *(float4*)op = o0;
            *(float4*)(op + 4) = o1;
        }
    }
}

// ---------------------------------------------------------------------------
// launch
// ---------------------------------------------------------------------------

extern "C" void kernel_launch(void* const* d_in, const int* in_sizes, int n_in,
                              void* d_out, int out_size, void* d_ws, size_t ws_size,
                              hipStream_t stream) {
    const float* x = (const float*)d_in[0];
    const int* ei = (const int*)d_in[1];
    const float* W1l = (const float*)d_in[2];
    const float* b1 = (const float*)d_in[3];
    const float* W1r = (const float*)d_in[4];
    const float* W2l = (const float*)d_in[5];
    const float* b2 = (const float*)d_in[6];
    const float* W2r = (const float*)d_in[7];
    float* out = (float*)d_out;

    const int* src = ei;
    const int* dst = ei + N_EDGES_C;

    // int workspace region (first 8 MiB)
    int* iw = (int*)d_ws;
    int* bucket_counts = iw;                      // 2048
    int* bucket_base = iw + 2048;                 // 2048 (NB+1 used)
    int* cursor = iw + 4096;                      // 2048
    unsigned* edge_pkt = (unsigned*)(iw + 6144);  // 1.6M ints -> ends 1606144
    u16* T1l = (u16*)(iw + 1606144);              // 4 x 32768 u16 = 256 KB
    u16* T1r = T1l + 32768;
    u16* T2l = T1r + 32768;
    u16* T2r = T2l + 32768;                       // ends ~6.7 MB < 8 MiB
    // bf16 region at byte offset 8 MiB; stride 12.85M u16 (pad for OOB tile reads
    // and the sentinel zero row at row 100000)
    u16* ub = (u16*)((char*)d_ws + (8u << 20));
    u16* x_bf = ub;                               // [100001][128]
    u16* p2 = ub + 12850000;                      // [100001][128]
    u16* outp = ub + 25700000;                    // [100000][128]

    hipMemsetAsync(bucket_counts, 0, 2048 * sizeof(int), stream);

    front_fused<<<CONV_BLOCKS + WB_BLOCKS + P1_BLOCKS + 1, 256, 0, stream>>>(
        x, dst, W1l, W1r, W2l, W2r, x_bf, T1l, T1r, T2l, T2r, bucket_counts, p2);
    bucket_scan<<<1, 1024, 0, stream>>>(bucket_counts, bucket_base, cursor);
    p2_scatter<<<(N_EDGES_C / 4 + 4095) / 4096, 1024, 0, stream>>>(src, dst, cursor,
                                                                   edge_pkt);

    // per bucket: sort + gather-mean + GEMM L1 + GEMM L2 -> p2, outp
    fused_gemm_agg<<<NB, 256, 0, stream>>>(x_bf, bucket_base, edge_pkt, T1l, T1r,
                                           T2l, T2r, b1, b2, p2, outp, N_NODES_C);
    // out = mean_{src->node} p2 + outp   (fp32)
    agg_final<<<NB, 256, 0, stream>>>(p2, bucket_base, edge_pkt, outp, out);
}